// Round 17
// baseline (59.281 us; speedup 1.0000x reference)
//
#include <hip/hip_runtime.h>
#include <hip/hip_bf16.h>

#define NH 4
#define HD 32
#define PAD 3
#define HW 56
#define NPIX (8*HW*HW)          // 25088 pixels
#define SCALE 0.17677669529663687f

// ---------------- workspace layout (bytes) ----------------
// qs    : bf16 [8][4][56][56][32]    6,422,528  (q, pre-scaled, bf16)
// kbuf  : bf16 [8][4][56][56][32]    6,422,528
// vbuf  : bf16 [8][4][56][56][32]    6,422,528
// xh    : bf16 [25088][128]          6,422,528  (attn bf16 from natt)
// W splits: qkv hi/lo 98,304 each; proj hi/lo 32,768 each
#define QS_OFF   0
#define K_OFF    12845056
#define V_OFF    (K_OFF + 6422528)
#define XH_OFF   (V_OFF + 6422528)      // attn (written by natt)
#define XL_OFF   (XH_OFF + 6422528)     // (unused)
#define WQH_OFF  (XL_OFF + 6422528)
#define WQL_OFF  (WQH_OFF + 98304)
#define WPH_OFF  (WQL_OFF + 98304)
#define WPL_OFF  (WPH_OFF + 32768)

typedef __attribute__((ext_vector_type(8))) short short8v;
typedef __attribute__((ext_vector_type(4))) float f32x4;

__device__ __forceinline__ float blo(unsigned u) { return __uint_as_float(u << 16); }
__device__ __forceinline__ float bhi(unsigned u) { return __uint_as_float(u & 0xffff0000u); }

__device__ __forceinline__ unsigned short f2b(float x) {       // f32 -> bf16 bits, RNE
    unsigned u = __float_as_uint(x);
    unsigned r = (u + 0x7fffu + ((u >> 16) & 1u)) >> 16;
    return (unsigned short)r;
}
__device__ __forceinline__ float b2f(unsigned short s) { return __uint_as_float((unsigned)s << 16); }

// two 4-length fma chains + final add (round-9 order)
__device__ __forceinline__ float dot8v(const float* q8, uint4 k) {
    float s0, s1;
    s0 = q8[0] * blo(k.x); s0 = fmaf(q8[1], bhi(k.x), s0);
    s0 = fmaf(q8[2], blo(k.y), s0); s0 = fmaf(q8[3], bhi(k.y), s0);
    s1 = q8[4] * blo(k.z); s1 = fmaf(q8[5], bhi(k.z), s1);
    s1 = fmaf(q8[6], blo(k.w), s1); s1 = fmaf(q8[7], bhi(k.w), s1);
    return s0 + s1;
}

// quad (4-lane) sum via DPP quad_perm: xor1 = 0xB1, xor2 = 0x4E. VALU-only.
__device__ __forceinline__ float quad_sum(float x) {
    x += __int_as_float(__builtin_amdgcn_update_dpp(0, __float_as_int(x), 0xB1, 0xF, 0xF, true));
    x += __int_as_float(__builtin_amdgcn_update_dpp(0, __float_as_int(x), 0x4E, 0xF, 0xF, true));
    return x;
}

// ---------------------------------------------------------------------------
// Pre-split (weights only): W_qkv 12288 f4 + W_proj 4096 f4 = 16384.
// ---------------------------------------------------------------------------
__global__ __launch_bounds__(256) void split_k(
    const float* __restrict__ wq, const float* __restrict__ wp,
    unsigned short* __restrict__ wqh, unsigned short* __restrict__ wql,
    unsigned short* __restrict__ wph, unsigned short* __restrict__ wpl)
{
    int idx = blockIdx.x * 256 + threadIdx.x;
    if (idx >= 16384) return;
    const float* src; unsigned short *dh, *dl; int off;
    if (idx < 12288) { src = wq; dh = wqh; dl = wql; off = idx; }
    else             { src = wp; dh = wph; dl = wpl; off = idx - 12288; }
    float4 v = ((const float4*)src)[off];
    ushort4 h, l;
    h.x = f2b(v.x); l.x = f2b(v.x - b2f(h.x));
    h.y = f2b(v.y); l.y = f2b(v.y - b2f(h.y));
    h.z = f2b(v.z); l.z = f2b(v.z - b2f(h.z));
    h.w = f2b(v.w); l.w = f2b(v.w - b2f(h.w));
    ((ushort4*)dh)[off] = h;
    ((ushort4*)dl)[off] = l;
}

// ---------------------------------------------------------------------------
// Fused-N MFMA GEMM, round-16 structure + LDS-repack epilogue for QKV:
// within a phase, sel = ph>>1 is UNIFORM and the 64x64 output slice maps to
// 2 contiguous 4KB regions (2 heads x 64 pixels x 32 d). Old epilogue: 96
// semi-scattered 2B stores/thread (the ~7us QKV overhead). New: 16 bf16 ->
// rep[64][72] LDS (72-stride: bank-rotated, conflict-free b128 reads),
// barrier, 2 coalesced uint4 stores/thread. Values bitwise-identical.
//  SELQKV=1: NPH=6, A = f32 x split hi/lo in-kernel; 3 MFMA/frag (bf16x2).
//  SELQKV=0: NPH=2, A = attn single bf16; 2 MFMA/frag; old f32-row epilogue.
// LDS: QKV 64KB + 9KB rep -> 2 blocks/CU; proj 48KB -> 3 blocks/CU.
// ---------------------------------------------------------------------------
template <int SELQKV>
__global__ __launch_bounds__(256, 2) void gemm_fused(
    const float* __restrict__ Af32,
    const unsigned short* __restrict__ Axh,
    const unsigned short* __restrict__ Bgh, const unsigned short* __restrict__ Bgl,
    const float* __restrict__ bias,
    unsigned short* __restrict__ outq, unsigned short* __restrict__ outk,
    unsigned short* __restrict__ outv, float* __restrict__ outp)
{
    __shared__ unsigned short sAh[64 * 128];
    __shared__ unsigned short sAl[SELQKV ? 64 * 128 : 64];   // unused for proj
    __shared__ unsigned short sBh[64 * 128];
    __shared__ unsigned short sBl[64 * 128];
    __shared__ unsigned short rep[SELQKV ? 64 * 72 : 64];    // repack buffer

    const int tid = threadIdx.x;
    const int m0 = blockIdx.x * 64;
    constexpr int NPH = SELQKV ? 6 : 2;

    // ---- stage A once ----
    if constexpr (SELQKV) {
#pragma unroll
        for (int it = 0; it < 8; ++it) {
            int idx = tid + it * 256;          // 0..2047 float4 chunks
            int row = idx >> 5;                // 0..63
            int c4  = idx & 31;
            float4 a = *(const float4*)(Af32 + (size_t)(m0 + row) * 128 + c4 * 4);
            int byte = (row * 256 + c4 * 8) ^ ((row & 7) << 4);
            ushort4 h, l;
            h.x = f2b(a.x); l.x = f2b(a.x - b2f(h.x));
            h.y = f2b(a.y); l.y = f2b(a.y - b2f(h.y));
            h.z = f2b(a.z); l.z = f2b(a.z - b2f(h.z));
            h.w = f2b(a.w); l.w = f2b(a.w - b2f(h.w));
            *(ushort4*)((char*)sAh + byte) = h;
            *(ushort4*)((char*)sAl + byte) = l;
        }
    } else {
#pragma unroll
        for (int it = 0; it < 4; ++it) {
            int chunk = it * 256 + tid;        // 0..1023
            int row = chunk >> 4, c16 = chunk & 15;
            int byte = (row * 256 + c16 * 16) ^ ((row & 7) << 4);
            size_t ga = (size_t)(m0 + row) * 128 + c16 * 8;
            *(uint4*)((char*)sAh + byte) = *(const uint4*)(Axh + ga);
        }
    }

    const int lane = tid & 63;
    const int w  = tid >> 6;
    const int wr = w >> 1, wc = w & 1;       // 2x2 waves -> 64x64
    const int fr  = lane & 15;
    const int kqb = (lane >> 4) * 16;        // k byte offset within 64B group
    const int cl = lane & 15;
    const int rq = lane >> 4;

    for (int ph = 0; ph < NPH; ++ph) {
        const int n0 = ph * 64;
        if (ph > 0) __syncthreads();         // prior mfma/rep reads done
#pragma unroll
        for (int it = 0; it < 4; ++it) {
            int chunk = it * 256 + tid;      // 0..1023
            int row = chunk >> 4, c16 = chunk & 15;
            int byte = (row * 256 + c16 * 16) ^ ((row & 7) << 4);
            size_t gb = (size_t)(n0 + row) * 128 + c16 * 8;
            *(uint4*)((char*)sBh + byte) = *(const uint4*)(Bgh + gb);
            *(uint4*)((char*)sBl + byte) = *(const uint4*)(Bgl + gb);
        }
        __syncthreads();

        f32x4 acc[2][2];
#pragma unroll
        for (int i = 0; i < 2; ++i)
#pragma unroll
            for (int j = 0; j < 2; ++j) acc[i][j] = (f32x4){0.f, 0.f, 0.f, 0.f};

#pragma unroll
        for (int ks = 0; ks < 4; ++ks) {
            short8v ah[2], al[2], bh[2], bl[2];
#pragma unroll
            for (int mi = 0; mi < 2; ++mi) {
                int row = wr * 32 + mi * 16 + fr;
                int byte = (row * 256 + ks * 64 + kqb) ^ ((row & 7) << 4);
                ah[mi] = *(const short8v*)((const char*)sAh + byte);
                if constexpr (SELQKV)
                    al[mi] = *(const short8v*)((const char*)sAl + byte);
            }
#pragma unroll
            for (int ni = 0; ni < 2; ++ni) {
                int row = wc * 32 + ni * 16 + fr;
                int byte = (row * 256 + ks * 64 + kqb) ^ ((row & 7) << 4);
                bh[ni] = *(const short8v*)((const char*)sBh + byte);
                bl[ni] = *(const short8v*)((const char*)sBl + byte);
            }
#pragma unroll
            for (int mi = 0; mi < 2; ++mi)
#pragma unroll
                for (int ni = 0; ni < 2; ++ni) {
                    acc[mi][ni] = __builtin_amdgcn_mfma_f32_16x16x32_bf16(ah[mi], bh[ni], acc[mi][ni], 0, 0, 0);
                    acc[mi][ni] = __builtin_amdgcn_mfma_f32_16x16x32_bf16(ah[mi], bl[ni], acc[mi][ni], 0, 0, 0);
                    if constexpr (SELQKV)
                        acc[mi][ni] = __builtin_amdgcn_mfma_f32_16x16x32_bf16(al[mi], bh[ni], acc[mi][ni], 0, 0, 0);
                }
        }

        // ---- epilogue: C/D layout col=lane&15, row=4*(lane>>4)+reg ----
        if constexpr (SELQKV) {
            const int sel = ph >> 1;          // 0=q 1=k 2=v (uniform per phase)
            unsigned short* dst = sel == 0 ? outq : (sel == 1 ? outk : outv);
            const int hbase = (ph & 1) * 2;
            // 1) repack 16 bf16 results into rep[64][72]
#pragma unroll
            for (int mi = 0; mi < 2; ++mi)
#pragma unroll
                for (int reg = 0; reg < 4; ++reg) {
                    int mloc = wr * 32 + mi * 16 + rq * 4 + reg;
#pragma unroll
                    for (int ni = 0; ni < 2; ++ni) {
                        int nloc = wc * 32 + ni * 16 + cl;
                        float val = acc[mi][ni][reg] + bias[n0 + nloc];
                        if (sel == 0) val *= SCALE;
                        rep[mloc * 72 + nloc] = f2b(val);
                    }
                }
            __syncthreads();
            // 2) coalesced stores: 512 uint4 chunks (2 heads x 64 px x 32 d)
            const int bb = m0 / 3136;         // block never straddles a batch
            const int pixbase = m0 - bb * 3136;
#pragma unroll
            for (int t = 0; t < 2; ++t) {
                int ch = tid + t * 256;       // 0..511
                int row = ch >> 3, c8 = ch & 7;
                int hl = c8 >> 2, d8 = (c8 & 3) * 8;
                uint4 v = *(const uint4*)(&rep[row * 72 + hl * 32 + d8]);
                size_t oi = ((size_t)((bb * NH + hbase + hl) * 3136) + pixbase + row) * 32 + d8;
                *(uint4*)(dst + oi) = v;
            }
        } else {
#pragma unroll
            for (int mi = 0; mi < 2; ++mi)
#pragma unroll
                for (int reg = 0; reg < 4; ++reg) {
                    int m = m0 + wr * 32 + mi * 16 + rq * 4 + reg;
#pragma unroll
                    for (int ni = 0; ni < 2; ++ni) {
                        int nn = n0 + wc * 32 + ni * 16 + cl;
                        outp[(size_t)m * 128 + nn] = acc[mi][ni][reg] + bias[nn];
                    }
                }
        }
    }
}

// ---------------------------------------------------------------------------
// Neighborhood attention v6c (round-16 version, unchanged — best measured):
// 4 threads per (pixel,head) d-chunk split, 256 thr, 8x8 tile, halo 14x14,
// grid 49x4x8.  V unpacked to f32 in LDS at staging (PV axpy = plain fmaf);
// K bf16 [pix][c]; dot as two 4-chains + add; q bf16 load hoisted (16B);
// attn output single bf16.  LDS 36.8 KB -> 4 blocks/CU = 16 waves/CU.
// ---------------------------------------------------------------------------
__global__ __launch_bounds__(256, 4) void natt_k(
    const unsigned short* __restrict__ qs, const unsigned short* __restrict__ kb,
    const unsigned short* __restrict__ vb, const float* __restrict__ rpb,
    unsigned short* __restrict__ attn_h)
{
    __shared__ uint4 ks[196 * 4];                    // K bf16 [pix][c], 12544 B
    __shared__ __align__(16) float vfs[4][1572];     // V f32 c-sections, 25152 B

    const int tid = threadIdx.x;
    const int b = blockIdx.z, h = blockIdx.y;
    const int tyy = blockIdx.x / 7, txx = blockIdx.x - tyy * 7;  // 7x7 tiles
    const int y0 = tyy * 8, x0 = txx * 8;
    const int bh = b * NH + h;

    const int p = tid >> 2, c = tid & 3;   // quads 4-aligned -> DPP partners co-active
    const int py = p >> 3;
    const int pxx = p & 7;

    // hoisted q load (bf16, 16B) — unpack once per thread
    float q[8];
    {
        uint4 qv = *(const uint4*)(qs +
            ((size_t)(bh * 3136) + (y0 + py) * 56 + (x0 + pxx)) * 32 + c * 8);
        q[0] = blo(qv.x); q[1] = bhi(qv.x); q[2] = blo(qv.y); q[3] = bhi(qv.y);
        q[4] = blo(qv.z); q[5] = bhi(qv.z); q[6] = blo(qv.w); q[7] = bhi(qv.w);
    }

    const uint4* kg = (const uint4*)kb;  // 4 uint4 per pixel (32 bf16)
    const uint4* vg = (const uint4*)vb;
    for (int idx = tid; idx < 784; idx += 256) {   // 196 pix * 4 chunks
        int pix = idx >> 2, cc = idx & 3;
        int i = pix / 14;
        int j = pix - i * 14;
        int y = y0 + i - PAD;
        int x = x0 + j - PAD;
        uint4 zk = make_uint4(0u, 0u, 0u, 0u);
        uint4 zv = make_uint4(0u, 0u, 0u, 0u);
        if ((unsigned)y < 56u && (unsigned)x < 56u) {
            int g = ((bh * 3136) + y * 56 + x) * 4 + cc;
            zk = kg[g];
            zv = vg[g];
        }
        ks[idx] = zk;
        float4 f0, f1;
        f0.x = blo(zv.x); f0.y = bhi(zv.x); f0.z = blo(zv.y); f0.w = bhi(zv.y);
        f1.x = blo(zv.z); f1.y = bhi(zv.z); f1.z = blo(zv.w); f1.w = bhi(zv.w);
        float* vd = &vfs[cc][pix * 8];
        *(float4*)(vd)     = f0;
        *(float4*)(vd + 4) = f1;
    }
    __syncthreads();

    float acc[8];
#pragma unroll
    for (int d = 0; d < 8; ++d) acc[d] = 0.f;
    float l = 0.f;

    const float* rph = rpb + h * 49;       // uniform index -> scalar loads
    const float* vbase = &vfs[c][0];

#pragma unroll
    for (int dy = 0; dy < 7; ++dy) {
        int rowpix = (py + dy) * 14 + pxx;
#pragma unroll
        for (int dx = 0; dx < 7; ++dx) {
            int pix = rowpix + dx;
            float s  = dot8v(q, ks[pix * 4 + c]);
            float sf = quad_sum(s) + rph[dy * 7 + dx];
            float e  = __expf(sf);
            l += e;
            const float* vv = vbase + pix * 8;
            float4 v0 = *(const float4*)(vv);
            float4 v1 = *(const float4*)(vv + 4);
            acc[0] = fmaf(e, v0.x, acc[0]); acc[1] = fmaf(e, v0.y, acc[1]);
            acc[2] = fmaf(e, v0.z, acc[2]); acc[3] = fmaf(e, v0.w, acc[3]);
            acc[4] = fmaf(e, v1.x, acc[4]); acc[5] = fmaf(e, v1.y, acc[5]);
            acc[6] = fmaf(e, v1.z, acc[6]); acc[7] = fmaf(e, v1.w, acc[7]);
        }
    }

    float rl = 1.0f / l;

    // pack 8 dims -> bf16 uint4, single b128 store
    unsigned short hv[8];
#pragma unroll
    for (int d = 0; d < 8; ++d) hv[d] = f2b(acc[d] * rl);
    uint4 uh;
    uh.x = (unsigned)hv[0] | ((unsigned)hv[1] << 16);
    uh.y = (unsigned)hv[2] | ((unsigned)hv[3] << 16);
    uh.z = (unsigned)hv[4] | ((unsigned)hv[5] << 16);
    uh.w = (unsigned)hv[6] | ((unsigned)hv[7] << 16);

    size_t base = ((size_t)(b * 3136) + (y0 + py) * 56 + (x0 + pxx)) * 128 + h * 32 + c * 8;
    *(uint4*)(attn_h + base) = uh;
}

extern "C" void kernel_launch(void* const* d_in, const int* in_sizes, int n_in,
                              void* d_out, int out_size, void* d_ws, size_t ws_size,
                              hipStream_t stream)
{
    const float* x     = (const float*)d_in[0];
    const float* Wqkv  = (const float*)d_in[1];
    const float* bqkv  = (const float*)d_in[2];
    const float* rpb   = (const float*)d_in[3];
    const float* Wproj = (const float*)d_in[4];
    const float* bproj = (const float*)d_in[5];
    float* out = (float*)d_out;

    char* ws = (char*)d_ws;
    unsigned short* qsb  = (unsigned short*)(ws + QS_OFF);   // q bf16 (pre-scaled)
    unsigned short* kbuf = (unsigned short*)(ws + K_OFF);
    unsigned short* vbuf = (unsigned short*)(ws + V_OFF);
    unsigned short* xh   = (unsigned short*)(ws + XH_OFF);   // attn bf16 (from natt)
    unsigned short* wqh  = (unsigned short*)(ws + WQH_OFF);
    unsigned short* wql  = (unsigned short*)(ws + WQL_OFF);
    unsigned short* wph  = (unsigned short*)(ws + WPH_OFF);
    unsigned short* wpl  = (unsigned short*)(ws + WPL_OFF);

    // 0) split weights into (hi,lo) bf16 (tiny)
    split_k<<<64, 256, 0, stream>>>(Wqkv, Wproj, wqh, wql, wph, wpl);

    // 1) QKV projection: 392 m-blocks, 6 internal n-phases (A staged once,
    //    LDS-repack coalesced epilogue)
    gemm_fused<1><<<392, 256, 0, stream>>>(x, nullptr, wqh, wql, bqkv,
                                           qsb, kbuf, vbuf, nullptr);

    // 2) neighborhood attention (v6c): 49 tiles x 4 heads x 8 batch, 256 thr
    natt_k<<<dim3(49, NH, 8), 256, 0, stream>>>(qsb, kbuf, vbuf, rpb, xh);

    // 3) output projection: 392 m-blocks, 2 internal n-phases, A = bf16 attn
    gemm_fused<0><<<392, 256, 0, stream>>>(nullptr, xh, wph, wpl, bproj,
                                           nullptr, nullptr, nullptr, out);
}

// Round 18
// 56.657 us; speedup vs baseline: 1.0463x; 1.0463x over previous
//
#include <hip/hip_runtime.h>
#include <hip/hip_bf16.h>

#define NH 4
#define HD 32
#define PAD 3
#define HW 56
#define NPIX (8*HW*HW)          // 25088 pixels
#define SCALE 0.17677669529663687f

// ---------------- workspace layout (bytes) ----------------
// qs    : bf16 [8][4][56][56][32]    6,422,528  (q, pre-scaled, bf16)
// kbuf  : bf16 [8][4][56][56][32]    6,422,528
// vbuf  : bf16 [8][4][56][56][32]    6,422,528
// xh    : bf16 [25088][128]          6,422,528  (attn bf16 from natt)
// W splits: qkv hi/lo 98,304 each; proj hi/lo 32,768 each
#define QS_OFF   0
#define K_OFF    12845056
#define V_OFF    (K_OFF + 6422528)
#define XH_OFF   (V_OFF + 6422528)      // attn (written by natt)
#define XL_OFF   (XH_OFF + 6422528)     // (unused)
#define WQH_OFF  (XL_OFF + 6422528)
#define WQL_OFF  (WQH_OFF + 98304)
#define WPH_OFF  (WQL_OFF + 98304)
#define WPL_OFF  (WPH_OFF + 32768)

typedef __attribute__((ext_vector_type(8))) short short8v;
typedef __attribute__((ext_vector_type(4))) float f32x4;

__device__ __forceinline__ float blo(unsigned u) { return __uint_as_float(u << 16); }
__device__ __forceinline__ float bhi(unsigned u) { return __uint_as_float(u & 0xffff0000u); }

__device__ __forceinline__ unsigned short f2b(float x) {       // f32 -> bf16 bits, RNE
    unsigned u = __float_as_uint(x);
    unsigned r = (u + 0x7fffu + ((u >> 16) & 1u)) >> 16;
    return (unsigned short)r;
}
__device__ __forceinline__ float b2f(unsigned short s) { return __uint_as_float((unsigned)s << 16); }

// two 4-length fma chains + final add (round-9 order)
__device__ __forceinline__ float dot8v(const float* q8, uint4 k) {
    float s0, s1;
    s0 = q8[0] * blo(k.x); s0 = fmaf(q8[1], bhi(k.x), s0);
    s0 = fmaf(q8[2], blo(k.y), s0); s0 = fmaf(q8[3], bhi(k.y), s0);
    s1 = q8[4] * blo(k.z); s1 = fmaf(q8[5], bhi(k.z), s1);
    s1 = fmaf(q8[6], blo(k.w), s1); s1 = fmaf(q8[7], bhi(k.w), s1);
    return s0 + s1;
}

// quad (4-lane) sum via DPP quad_perm: xor1 = 0xB1, xor2 = 0x4E. VALU-only.
__device__ __forceinline__ float quad_sum(float x) {
    x += __int_as_float(__builtin_amdgcn_update_dpp(0, __float_as_int(x), 0xB1, 0xF, 0xF, true));
    x += __int_as_float(__builtin_amdgcn_update_dpp(0, __float_as_int(x), 0x4E, 0xF, 0xF, true));
    return x;
}

// ---------------------------------------------------------------------------
// Pre-split (weights only): W_qkv 12288 f4 + W_proj 4096 f4 = 16384.
// ---------------------------------------------------------------------------
__global__ __launch_bounds__(256) void split_k(
    const float* __restrict__ wq, const float* __restrict__ wp,
    unsigned short* __restrict__ wqh, unsigned short* __restrict__ wql,
    unsigned short* __restrict__ wph, unsigned short* __restrict__ wpl)
{
    int idx = blockIdx.x * 256 + threadIdx.x;
    if (idx >= 16384) return;
    const float* src; unsigned short *dh, *dl; int off;
    if (idx < 12288) { src = wq; dh = wqh; dl = wql; off = idx; }
    else             { src = wp; dh = wph; dl = wpl; off = idx - 12288; }
    float4 v = ((const float4*)src)[off];
    ushort4 h, l;
    h.x = f2b(v.x); l.x = f2b(v.x - b2f(h.x));
    h.y = f2b(v.y); l.y = f2b(v.y - b2f(h.y));
    h.z = f2b(v.z); l.z = f2b(v.z - b2f(h.z));
    h.w = f2b(v.w); l.w = f2b(v.w - b2f(h.w));
    ((ushort4*)dh)[off] = h;
    ((ushort4*)dl)[off] = l;
}

// ---------------------------------------------------------------------------
// Fused-N MFMA GEMM, round-16 structure; A is now SINGLE bf16 for BOTH
// kernels (accuracy analysis: x-lo corrects ~0.2% relative — same order as
// the k/v bf16 output quantization we already accept; proj A was already
// single bf16). acc = Ah*Bh + Ah*Bl (2 MFMA/frag; W keeps hi/lo precision).
// LDS 48 KB (3 x 64x128 u16) -> up to 3 blocks/CU.
//  SELQKV=1: NPH=6, A = f32 x -> hi bf16 in-kernel; q/k/v scatter epilogue.
//  SELQKV=0: NPH=2, A = attn bf16; f32-row epilogue.
// LDS XOR swizzle byte ^= (row&7)<<4 -> conflict-free b128 reads.
// ---------------------------------------------------------------------------
template <int SELQKV>
__global__ __launch_bounds__(256, 2) void gemm_fused(
    const float* __restrict__ Af32,
    const unsigned short* __restrict__ Axh,
    const unsigned short* __restrict__ Bgh, const unsigned short* __restrict__ Bgl,
    const float* __restrict__ bias,
    unsigned short* __restrict__ outq, unsigned short* __restrict__ outk,
    unsigned short* __restrict__ outv, float* __restrict__ outp)
{
    __shared__ unsigned short sAh[64 * 128];
    __shared__ unsigned short sBh[64 * 128];
    __shared__ unsigned short sBl[64 * 128];

    const int tid = threadIdx.x;
    const int m0 = blockIdx.x * 64;
    constexpr int NPH = SELQKV ? 6 : 2;

    // ---- stage A once (hi bf16 only) ----
    if constexpr (SELQKV) {
#pragma unroll
        for (int it = 0; it < 8; ++it) {
            int idx = tid + it * 256;          // 0..2047 float4 chunks
            int row = idx >> 5;                // 0..63
            int c4  = idx & 31;
            float4 a = *(const float4*)(Af32 + (size_t)(m0 + row) * 128 + c4 * 4);
            int byte = (row * 256 + c4 * 8) ^ ((row & 7) << 4);
            ushort4 h;
            h.x = f2b(a.x); h.y = f2b(a.y); h.z = f2b(a.z); h.w = f2b(a.w);
            *(ushort4*)((char*)sAh + byte) = h;
        }
    } else {
#pragma unroll
        for (int it = 0; it < 4; ++it) {
            int chunk = it * 256 + tid;        // 0..1023
            int row = chunk >> 4, c16 = chunk & 15;
            int byte = (row * 256 + c16 * 16) ^ ((row & 7) << 4);
            size_t ga = (size_t)(m0 + row) * 128 + c16 * 8;
            *(uint4*)((char*)sAh + byte) = *(const uint4*)(Axh + ga);
        }
    }

    const int lane = tid & 63;
    const int w  = tid >> 6;
    const int wr = w >> 1, wc = w & 1;       // 2x2 waves -> 64x64
    const int fr  = lane & 15;
    const int kqb = (lane >> 4) * 16;        // k byte offset within 64B group
    const int cl = lane & 15;
    const int rq = lane >> 4;

    for (int ph = 0; ph < NPH; ++ph) {
        const int n0 = ph * 64;
        if (ph > 0) __syncthreads();         // prior mfma reads done before B overwrite
#pragma unroll
        for (int it = 0; it < 4; ++it) {
            int chunk = it * 256 + tid;      // 0..1023
            int row = chunk >> 4, c16 = chunk & 15;
            int byte = (row * 256 + c16 * 16) ^ ((row & 7) << 4);
            size_t gb = (size_t)(n0 + row) * 128 + c16 * 8;
            *(uint4*)((char*)sBh + byte) = *(const uint4*)(Bgh + gb);
            *(uint4*)((char*)sBl + byte) = *(const uint4*)(Bgl + gb);
        }
        __syncthreads();

        f32x4 acc[2][2];
#pragma unroll
        for (int i = 0; i < 2; ++i)
#pragma unroll
            for (int j = 0; j < 2; ++j) acc[i][j] = (f32x4){0.f, 0.f, 0.f, 0.f};

#pragma unroll
        for (int ks = 0; ks < 4; ++ks) {
            short8v ah[2], bh[2], bl[2];
#pragma unroll
            for (int mi = 0; mi < 2; ++mi) {
                int row = wr * 32 + mi * 16 + fr;
                int byte = (row * 256 + ks * 64 + kqb) ^ ((row & 7) << 4);
                ah[mi] = *(const short8v*)((const char*)sAh + byte);
            }
#pragma unroll
            for (int ni = 0; ni < 2; ++ni) {
                int row = wc * 32 + ni * 16 + fr;
                int byte = (row * 256 + ks * 64 + kqb) ^ ((row & 7) << 4);
                bh[ni] = *(const short8v*)((const char*)sBh + byte);
                bl[ni] = *(const short8v*)((const char*)sBl + byte);
            }
#pragma unroll
            for (int mi = 0; mi < 2; ++mi)
#pragma unroll
                for (int ni = 0; ni < 2; ++ni) {
                    acc[mi][ni] = __builtin_amdgcn_mfma_f32_16x16x32_bf16(ah[mi], bh[ni], acc[mi][ni], 0, 0, 0);
                    acc[mi][ni] = __builtin_amdgcn_mfma_f32_16x16x32_bf16(ah[mi], bl[ni], acc[mi][ni], 0, 0, 0);
                }
        }

        // ---- epilogue: C/D layout col=lane&15, row=4*(lane>>4)+reg ----
#pragma unroll
        for (int mi = 0; mi < 2; ++mi) {
#pragma unroll
            for (int reg = 0; reg < 4; ++reg) {
                int m = m0 + wr * 32 + mi * 16 + rq * 4 + reg;
                if constexpr (SELQKV) {
                    int b = m / 3136;
                    int r = m - b * 3136;
                    int y = r / 56;
                    int x = r - y * 56;
#pragma unroll
                    for (int ni = 0; ni < 2; ++ni) {
                        int nn = n0 + wc * 32 + ni * 16 + cl;   // 0..383
                        float val = acc[mi][ni][reg] + bias[nn];
                        int sel = nn >> 7;                      // 0=q 1=k 2=v
                        int nl = nn & 127;
                        int h = nl >> 5, d = nl & 31;
                        size_t oi = ((size_t)((b * NH + h) * 3136) + y * 56 + x) * 32 + d;
                        if (sel == 0)      outq[oi] = f2b(val * SCALE);   // q bf16
                        else if (sel == 1) outk[oi] = f2b(val);
                        else               outv[oi] = f2b(val);
                    }
                } else {
#pragma unroll
                    for (int ni = 0; ni < 2; ++ni) {
                        int nn = n0 + wc * 32 + ni * 16 + cl;
                        outp[(size_t)m * 128 + nn] = acc[mi][ni][reg] + bias[nn];
                    }
                }
            }
        }
    }
}

// ---------------------------------------------------------------------------
// Neighborhood attention v6c (round-16 version, unchanged — best measured):
// 4 threads per (pixel,head) d-chunk split, 256 thr, 8x8 tile, halo 14x14,
// grid 49x4x8.  V unpacked to f32 in LDS at staging (PV axpy = plain fmaf);
// K bf16 [pix][c]; dot as two 4-chains + add; q bf16 load hoisted (16B);
// attn output single bf16.  LDS 36.8 KB -> 4 blocks/CU = 16 waves/CU.
// ---------------------------------------------------------------------------
__global__ __launch_bounds__(256, 4) void natt_k(
    const unsigned short* __restrict__ qs, const unsigned short* __restrict__ kb,
    const unsigned short* __restrict__ vb, const float* __restrict__ rpb,
    unsigned short* __restrict__ attn_h)
{
    __shared__ uint4 ks[196 * 4];                    // K bf16 [pix][c], 12544 B
    __shared__ __align__(16) float vfs[4][1572];     // V f32 c-sections, 25152 B

    const int tid = threadIdx.x;
    const int b = blockIdx.z, h = blockIdx.y;
    const int tyy = blockIdx.x / 7, txx = blockIdx.x - tyy * 7;  // 7x7 tiles
    const int y0 = tyy * 8, x0 = txx * 8;
    const int bh = b * NH + h;

    const int p = tid >> 2, c = tid & 3;   // quads 4-aligned -> DPP partners co-active
    const int py = p >> 3;
    const int pxx = p & 7;

    // hoisted q load (bf16, 16B) — unpack once per thread
    float q[8];
    {
        uint4 qv = *(const uint4*)(qs +
            ((size_t)(bh * 3136) + (y0 + py) * 56 + (x0 + pxx)) * 32 + c * 8);
        q[0] = blo(qv.x); q[1] = bhi(qv.x); q[2] = blo(qv.y); q[3] = bhi(qv.y);
        q[4] = blo(qv.z); q[5] = bhi(qv.z); q[6] = blo(qv.w); q[7] = bhi(qv.w);
    }

    const uint4* kg = (const uint4*)kb;  // 4 uint4 per pixel (32 bf16)
    const uint4* vg = (const uint4*)vb;
    for (int idx = tid; idx < 784; idx += 256) {   // 196 pix * 4 chunks
        int pix = idx >> 2, cc = idx & 3;
        int i = pix / 14;
        int j = pix - i * 14;
        int y = y0 + i - PAD;
        int x = x0 + j - PAD;
        uint4 zk = make_uint4(0u, 0u, 0u, 0u);
        uint4 zv = make_uint4(0u, 0u, 0u, 0u);
        if ((unsigned)y < 56u && (unsigned)x < 56u) {
            int g = ((bh * 3136) + y * 56 + x) * 4 + cc;
            zk = kg[g];
            zv = vg[g];
        }
        ks[idx] = zk;
        float4 f0, f1;
        f0.x = blo(zv.x); f0.y = bhi(zv.x); f0.z = blo(zv.y); f0.w = bhi(zv.y);
        f1.x = blo(zv.z); f1.y = bhi(zv.z); f1.z = blo(zv.w); f1.w = bhi(zv.w);
        float* vd = &vfs[cc][pix * 8];
        *(float4*)(vd)     = f0;
        *(float4*)(vd + 4) = f1;
    }
    __syncthreads();

    float acc[8];
#pragma unroll
    for (int d = 0; d < 8; ++d) acc[d] = 0.f;
    float l = 0.f;

    const float* rph = rpb + h * 49;       // uniform index -> scalar loads
    const float* vbase = &vfs[c][0];

#pragma unroll
    for (int dy = 0; dy < 7; ++dy) {
        int rowpix = (py + dy) * 14 + pxx;
#pragma unroll
        for (int dx = 0; dx < 7; ++dx) {
            int pix = rowpix + dx;
            float s  = dot8v(q, ks[pix * 4 + c]);
            float sf = quad_sum(s) + rph[dy * 7 + dx];
            float e  = __expf(sf);
            l += e;
            const float* vv = vbase + pix * 8;
            float4 v0 = *(const float4*)(vv);
            float4 v1 = *(const float4*)(vv + 4);
            acc[0] = fmaf(e, v0.x, acc[0]); acc[1] = fmaf(e, v0.y, acc[1]);
            acc[2] = fmaf(e, v0.z, acc[2]); acc[3] = fmaf(e, v0.w, acc[3]);
            acc[4] = fmaf(e, v1.x, acc[4]); acc[5] = fmaf(e, v1.y, acc[5]);
            acc[6] = fmaf(e, v1.z, acc[6]); acc[7] = fmaf(e, v1.w, acc[7]);
        }
    }

    float rl = 1.0f / l;

    // pack 8 dims -> bf16 uint4, single b128 store
    unsigned short hv[8];
#pragma unroll
    for (int d = 0; d < 8; ++d) hv[d] = f2b(acc[d] * rl);
    uint4 uh;
    uh.x = (unsigned)hv[0] | ((unsigned)hv[1] << 16);
    uh.y = (unsigned)hv[2] | ((unsigned)hv[3] << 16);
    uh.z = (unsigned)hv[4] | ((unsigned)hv[5] << 16);
    uh.w = (unsigned)hv[6] | ((unsigned)hv[7] << 16);

    size_t base = ((size_t)(b * 3136) + (y0 + py) * 56 + (x0 + pxx)) * 128 + h * 32 + c * 8;
    *(uint4*)(attn_h + base) = uh;
}

extern "C" void kernel_launch(void* const* d_in, const int* in_sizes, int n_in,
                              void* d_out, int out_size, void* d_ws, size_t ws_size,
                              hipStream_t stream)
{
    const float* x     = (const float*)d_in[0];
    const float* Wqkv  = (const float*)d_in[1];
    const float* bqkv  = (const float*)d_in[2];
    const float* rpb   = (const float*)d_in[3];
    const float* Wproj = (const float*)d_in[4];
    const float* bproj = (const float*)d_in[5];
    float* out = (float*)d_out;

    char* ws = (char*)d_ws;
    unsigned short* qsb  = (unsigned short*)(ws + QS_OFF);   // q bf16 (pre-scaled)
    unsigned short* kbuf = (unsigned short*)(ws + K_OFF);
    unsigned short* vbuf = (unsigned short*)(ws + V_OFF);
    unsigned short* xh   = (unsigned short*)(ws + XH_OFF);   // attn bf16 (from natt)
    unsigned short* wqh  = (unsigned short*)(ws + WQH_OFF);
    unsigned short* wql  = (unsigned short*)(ws + WQL_OFF);
    unsigned short* wph  = (unsigned short*)(ws + WPH_OFF);
    unsigned short* wpl  = (unsigned short*)(ws + WPL_OFF);

    // 0) split weights into (hi,lo) bf16 (tiny)
    split_k<<<64, 256, 0, stream>>>(Wqkv, Wproj, wqh, wql, wph, wpl);

    // 1) QKV projection: 392 m-blocks, 6 internal n-phases (A staged once,
    //    A = x-hi bf16 only; W keeps hi/lo -> 2 MFMA/frag)
    gemm_fused<1><<<392, 256, 0, stream>>>(x, nullptr, wqh, wql, bqkv,
                                           qsb, kbuf, vbuf, nullptr);

    // 2) neighborhood attention (v6c): 49 tiles x 4 heads x 8 batch, 256 thr
    natt_k<<<dim3(49, NH, 8), 256, 0, stream>>>(qsb, kbuf, vbuf, rpb, xh);

    // 3) output projection: 392 m-blocks, 2 internal n-phases, A = bf16 attn
    gemm_fused<0><<<392, 256, 0, stream>>>(nullptr, xh, wph, wpl, bproj,
                                           nullptr, nullptr, nullptr, out);
}

// Round 19
// 53.849 us; speedup vs baseline: 1.1009x; 1.0521x over previous
//
#include <hip/hip_runtime.h>
#include <hip/hip_bf16.h>

#define NH 4
#define HD 32
#define PAD 3
#define HW 56
#define NPIX (8*HW*HW)          // 25088 pixels
#define SCALE 0.17677669529663687f

// ---------------- workspace layout (bytes) ----------------
// qs    : bf16 [8][4][56][56][32]    6,422,528  (q, pre-scaled, bf16)
// kbuf  : bf16 [8][4][56][56][32]    6,422,528
// vbuf  : bf16 [8][4][56][56][32]    6,422,528
// xh    : bf16 [25088][128]          6,422,528  (attn bf16 from natt)
// W bf16: wqh 98,304; wph 32,768
#define QS_OFF   0
#define K_OFF    12845056
#define V_OFF    (K_OFF + 6422528)
#define XH_OFF   (V_OFF + 6422528)      // attn (written by natt)
#define XL_OFF   (XH_OFF + 6422528)     // (unused)
#define WQH_OFF  (XL_OFF + 6422528)
#define WPH_OFF  (WQH_OFF + 98304)

typedef __attribute__((ext_vector_type(8))) short short8v;
typedef __attribute__((ext_vector_type(4))) float f32x4;

__device__ __forceinline__ float blo(unsigned u) { return __uint_as_float(u << 16); }
__device__ __forceinline__ float bhi(unsigned u) { return __uint_as_float(u & 0xffff0000u); }

__device__ __forceinline__ unsigned short f2b(float x) {       // f32 -> bf16 bits, RNE
    unsigned u = __float_as_uint(x);
    unsigned r = (u + 0x7fffu + ((u >> 16) & 1u)) >> 16;
    return (unsigned short)r;
}
__device__ __forceinline__ float b2f(unsigned short s) { return __uint_as_float((unsigned)s << 16); }

// two 4-length fma chains + final add (round-9 order)
__device__ __forceinline__ float dot8v(const float* q8, uint4 k) {
    float s0, s1;
    s0 = q8[0] * blo(k.x); s0 = fmaf(q8[1], bhi(k.x), s0);
    s0 = fmaf(q8[2], blo(k.y), s0); s0 = fmaf(q8[3], bhi(k.y), s0);
    s1 = q8[4] * blo(k.z); s1 = fmaf(q8[5], bhi(k.z), s1);
    s1 = fmaf(q8[6], blo(k.w), s1); s1 = fmaf(q8[7], bhi(k.w), s1);
    return s0 + s1;
}

// quad (4-lane) sum via DPP quad_perm: xor1 = 0xB1, xor2 = 0x4E. VALU-only.
__device__ __forceinline__ float quad_sum(float x) {
    x += __int_as_float(__builtin_amdgcn_update_dpp(0, __float_as_int(x), 0xB1, 0xF, 0xF, true));
    x += __int_as_float(__builtin_amdgcn_update_dpp(0, __float_as_int(x), 0x4E, 0xF, 0xF, true));
    return x;
}

// ---------------------------------------------------------------------------
// Weight convert (f32 -> bf16 hi only): W_qkv 12288 f4 + W_proj 4096 f4.
// ---------------------------------------------------------------------------
__global__ __launch_bounds__(256) void split_k(
    const float* __restrict__ wq, const float* __restrict__ wp,
    unsigned short* __restrict__ wqh, unsigned short* __restrict__ wph)
{
    int idx = blockIdx.x * 256 + threadIdx.x;
    if (idx >= 16384) return;
    const float* src; unsigned short* dh; int off;
    if (idx < 12288) { src = wq; dh = wqh; off = idx; }
    else             { src = wp; dh = wph; off = idx - 12288; }
    float4 v = ((const float4*)src)[off];
    ushort4 h;
    h.x = f2b(v.x); h.y = f2b(v.y); h.z = f2b(v.z); h.w = f2b(v.w);
    ((ushort4*)dh)[off] = h;
}

// ---------------------------------------------------------------------------
// Fused-N MFMA GEMM, plain bf16 (1 MFMA/frag). Accuracy: three rounds of
// precision-descent (q bf16, attn bf16, x-hi-only) left absmax pinned at the
// k/v output-quantization floor (2.44e-4, 3.6x margin); W-lo drop adds a
// second ~2^-9-relative term -> predicted absmax 4-6e-4, inside 8.79e-4.
// grid = 392 m-blocks; A-tile staged once; NPH n-phases restage 16 KB B.
//  SELQKV=1: NPH=6, A = f32 x -> bf16 in-kernel; q/k/v scatter epilogue.
//  SELQKV=0: NPH=2, A = attn bf16; f32-row epilogue.
// LDS 32 KB -> up to 5 blocks/CU.  XOR swizzle byte ^= (row&7)<<4.
// ---------------------------------------------------------------------------
template <int SELQKV>
__global__ __launch_bounds__(256, 2) void gemm_fused(
    const float* __restrict__ Af32,
    const unsigned short* __restrict__ Axh,
    const unsigned short* __restrict__ Bgh,
    const float* __restrict__ bias,
    unsigned short* __restrict__ outq, unsigned short* __restrict__ outk,
    unsigned short* __restrict__ outv, float* __restrict__ outp)
{
    __shared__ unsigned short sAh[64 * 128];
    __shared__ unsigned short sBh[64 * 128];

    const int tid = threadIdx.x;
    const int m0 = blockIdx.x * 64;
    constexpr int NPH = SELQKV ? 6 : 2;

    // ---- stage A once (bf16) ----
    if constexpr (SELQKV) {
#pragma unroll
        for (int it = 0; it < 8; ++it) {
            int idx = tid + it * 256;          // 0..2047 float4 chunks
            int row = idx >> 5;                // 0..63
            int c4  = idx & 31;
            float4 a = *(const float4*)(Af32 + (size_t)(m0 + row) * 128 + c4 * 4);
            int byte = (row * 256 + c4 * 8) ^ ((row & 7) << 4);
            ushort4 h;
            h.x = f2b(a.x); h.y = f2b(a.y); h.z = f2b(a.z); h.w = f2b(a.w);
            *(ushort4*)((char*)sAh + byte) = h;
        }
    } else {
#pragma unroll
        for (int it = 0; it < 4; ++it) {
            int chunk = it * 256 + tid;        // 0..1023
            int row = chunk >> 4, c16 = chunk & 15;
            int byte = (row * 256 + c16 * 16) ^ ((row & 7) << 4);
            size_t ga = (size_t)(m0 + row) * 128 + c16 * 8;
            *(uint4*)((char*)sAh + byte) = *(const uint4*)(Axh + ga);
        }
    }

    const int lane = tid & 63;
    const int w  = tid >> 6;
    const int wr = w >> 1, wc = w & 1;       // 2x2 waves -> 64x64
    const int fr  = lane & 15;
    const int kqb = (lane >> 4) * 16;        // k byte offset within 64B group
    const int cl = lane & 15;
    const int rq = lane >> 4;

    for (int ph = 0; ph < NPH; ++ph) {
        const int n0 = ph * 64;
        if (ph > 0) __syncthreads();         // prior mfma reads done before B overwrite
#pragma unroll
        for (int it = 0; it < 4; ++it) {
            int chunk = it * 256 + tid;      // 0..1023
            int row = chunk >> 4, c16 = chunk & 15;
            int byte = (row * 256 + c16 * 16) ^ ((row & 7) << 4);
            size_t gb = (size_t)(n0 + row) * 128 + c16 * 8;
            *(uint4*)((char*)sBh + byte) = *(const uint4*)(Bgh + gb);
        }
        __syncthreads();

        f32x4 acc[2][2];
#pragma unroll
        for (int i = 0; i < 2; ++i)
#pragma unroll
            for (int j = 0; j < 2; ++j) acc[i][j] = (f32x4){0.f, 0.f, 0.f, 0.f};

#pragma unroll
        for (int ks = 0; ks < 4; ++ks) {
            short8v ah[2], bh[2];
#pragma unroll
            for (int mi = 0; mi < 2; ++mi) {
                int row = wr * 32 + mi * 16 + fr;
                int byte = (row * 256 + ks * 64 + kqb) ^ ((row & 7) << 4);
                ah[mi] = *(const short8v*)((const char*)sAh + byte);
            }
#pragma unroll
            for (int ni = 0; ni < 2; ++ni) {
                int row = wc * 32 + ni * 16 + fr;
                int byte = (row * 256 + ks * 64 + kqb) ^ ((row & 7) << 4);
                bh[ni] = *(const short8v*)((const char*)sBh + byte);
            }
#pragma unroll
            for (int mi = 0; mi < 2; ++mi)
#pragma unroll
                for (int ni = 0; ni < 2; ++ni)
                    acc[mi][ni] = __builtin_amdgcn_mfma_f32_16x16x32_bf16(ah[mi], bh[ni], acc[mi][ni], 0, 0, 0);
        }

        // ---- epilogue: C/D layout col=lane&15, row=4*(lane>>4)+reg ----
#pragma unroll
        for (int mi = 0; mi < 2; ++mi) {
#pragma unroll
            for (int reg = 0; reg < 4; ++reg) {
                int m = m0 + wr * 32 + mi * 16 + rq * 4 + reg;
                if constexpr (SELQKV) {
                    int b = m / 3136;
                    int r = m - b * 3136;
                    int y = r / 56;
                    int x = r - y * 56;
#pragma unroll
                    for (int ni = 0; ni < 2; ++ni) {
                        int nn = n0 + wc * 32 + ni * 16 + cl;   // 0..383
                        float val = acc[mi][ni][reg] + bias[nn];
                        int sel = nn >> 7;                      // 0=q 1=k 2=v
                        int nl = nn & 127;
                        int h = nl >> 5, d = nl & 31;
                        size_t oi = ((size_t)((b * NH + h) * 3136) + y * 56 + x) * 32 + d;
                        if (sel == 0)      outq[oi] = f2b(val * SCALE);   // q bf16
                        else if (sel == 1) outk[oi] = f2b(val);
                        else               outv[oi] = f2b(val);
                    }
                } else {
#pragma unroll
                    for (int ni = 0; ni < 2; ++ni) {
                        int nn = n0 + wc * 32 + ni * 16 + cl;
                        outp[(size_t)m * 128 + nn] = acc[mi][ni][reg] + bias[nn];
                    }
                }
            }
        }
    }
}

// ---------------------------------------------------------------------------
// Neighborhood attention v6c (round-16/18 version, unchanged — best measured):
// 4 threads per (pixel,head) d-chunk split, 256 thr, 8x8 tile, halo 14x14,
// grid 49x4x8.  V unpacked to f32 in LDS at staging (PV axpy = plain fmaf);
// K bf16 [pix][c]; dot as two 4-chains + add; q bf16 load hoisted (16B);
// attn output single bf16.  LDS 36.8 KB -> 4 blocks/CU = 16 waves/CU.
// ---------------------------------------------------------------------------
__global__ __launch_bounds__(256, 4) void natt_k(
    const unsigned short* __restrict__ qs, const unsigned short* __restrict__ kb,
    const unsigned short* __restrict__ vb, const float* __restrict__ rpb,
    unsigned short* __restrict__ attn_h)
{
    __shared__ uint4 ks[196 * 4];                    // K bf16 [pix][c], 12544 B
    __shared__ __align__(16) float vfs[4][1572];     // V f32 c-sections, 25152 B

    const int tid = threadIdx.x;
    const int b = blockIdx.z, h = blockIdx.y;
    const int tyy = blockIdx.x / 7, txx = blockIdx.x - tyy * 7;  // 7x7 tiles
    const int y0 = tyy * 8, x0 = txx * 8;
    const int bh = b * NH + h;

    const int p = tid >> 2, c = tid & 3;   // quads 4-aligned -> DPP partners co-active
    const int py = p >> 3;
    const int pxx = p & 7;

    // hoisted q load (bf16, 16B) — unpack once per thread
    float q[8];
    {
        uint4 qv = *(const uint4*)(qs +
            ((size_t)(bh * 3136) + (y0 + py) * 56 + (x0 + pxx)) * 32 + c * 8);
        q[0] = blo(qv.x); q[1] = bhi(qv.x); q[2] = blo(qv.y); q[3] = bhi(qv.y);
        q[4] = blo(qv.z); q[5] = bhi(qv.z); q[6] = blo(qv.w); q[7] = bhi(qv.w);
    }

    const uint4* kg = (const uint4*)kb;  // 4 uint4 per pixel (32 bf16)
    const uint4* vg = (const uint4*)vb;
    for (int idx = tid; idx < 784; idx += 256) {   // 196 pix * 4 chunks
        int pix = idx >> 2, cc = idx & 3;
        int i = pix / 14;
        int j = pix - i * 14;
        int y = y0 + i - PAD;
        int x = x0 + j - PAD;
        uint4 zk = make_uint4(0u, 0u, 0u, 0u);
        uint4 zv = make_uint4(0u, 0u, 0u, 0u);
        if ((unsigned)y < 56u && (unsigned)x < 56u) {
            int g = ((bh * 3136) + y * 56 + x) * 4 + cc;
            zk = kg[g];
            zv = vg[g];
        }
        ks[idx] = zk;
        float4 f0, f1;
        f0.x = blo(zv.x); f0.y = bhi(zv.x); f0.z = blo(zv.y); f0.w = bhi(zv.y);
        f1.x = blo(zv.z); f1.y = bhi(zv.z); f1.z = blo(zv.w); f1.w = bhi(zv.w);
        float* vd = &vfs[cc][pix * 8];
        *(float4*)(vd)     = f0;
        *(float4*)(vd + 4) = f1;
    }
    __syncthreads();

    float acc[8];
#pragma unroll
    for (int d = 0; d < 8; ++d) acc[d] = 0.f;
    float l = 0.f;

    const float* rph = rpb + h * 49;       // uniform index -> scalar loads
    const float* vbase = &vfs[c][0];

#pragma unroll
    for (int dy = 0; dy < 7; ++dy) {
        int rowpix = (py + dy) * 14 + pxx;
#pragma unroll
        for (int dx = 0; dx < 7; ++dx) {
            int pix = rowpix + dx;
            float s  = dot8v(q, ks[pix * 4 + c]);
            float sf = quad_sum(s) + rph[dy * 7 + dx];
            float e  = __expf(sf);
            l += e;
            const float* vv = vbase + pix * 8;
            float4 v0 = *(const float4*)(vv);
            float4 v1 = *(const float4*)(vv + 4);
            acc[0] = fmaf(e, v0.x, acc[0]); acc[1] = fmaf(e, v0.y, acc[1]);
            acc[2] = fmaf(e, v0.z, acc[2]); acc[3] = fmaf(e, v0.w, acc[3]);
            acc[4] = fmaf(e, v1.x, acc[4]); acc[5] = fmaf(e, v1.y, acc[5]);
            acc[6] = fmaf(e, v1.z, acc[6]); acc[7] = fmaf(e, v1.w, acc[7]);
        }
    }

    float rl = 1.0f / l;

    // pack 8 dims -> bf16 uint4, single b128 store
    unsigned short hv[8];
#pragma unroll
    for (int d = 0; d < 8; ++d) hv[d] = f2b(acc[d] * rl);
    uint4 uh;
    uh.x = (unsigned)hv[0] | ((unsigned)hv[1] << 16);
    uh.y = (unsigned)hv[2] | ((unsigned)hv[3] << 16);
    uh.z = (unsigned)hv[4] | ((unsigned)hv[5] << 16);
    uh.w = (unsigned)hv[6] | ((unsigned)hv[7] << 16);

    size_t base = ((size_t)(b * 3136) + (y0 + py) * 56 + (x0 + pxx)) * 128 + h * 32 + c * 8;
    *(uint4*)(attn_h + base) = uh;
}

extern "C" void kernel_launch(void* const* d_in, const int* in_sizes, int n_in,
                              void* d_out, int out_size, void* d_ws, size_t ws_size,
                              hipStream_t stream)
{
    const float* x     = (const float*)d_in[0];
    const float* Wqkv  = (const float*)d_in[1];
    const float* bqkv  = (const float*)d_in[2];
    const float* rpb   = (const float*)d_in[3];
    const float* Wproj = (const float*)d_in[4];
    const float* bproj = (const float*)d_in[5];
    float* out = (float*)d_out;

    char* ws = (char*)d_ws;
    unsigned short* qsb  = (unsigned short*)(ws + QS_OFF);   // q bf16 (pre-scaled)
    unsigned short* kbuf = (unsigned short*)(ws + K_OFF);
    unsigned short* vbuf = (unsigned short*)(ws + V_OFF);
    unsigned short* xh   = (unsigned short*)(ws + XH_OFF);   // attn bf16 (from natt)
    unsigned short* wqh  = (unsigned short*)(ws + WQH_OFF);
    unsigned short* wph  = (unsigned short*)(ws + WPH_OFF);

    // 0) convert weights to bf16 (tiny)
    split_k<<<64, 256, 0, stream>>>(Wqkv, Wproj, wqh, wph);

    // 1) QKV projection: 392 m-blocks, 6 internal n-phases (A staged once,
    //    plain bf16 -> 1 MFMA/frag, 32 KB LDS)
    gemm_fused<1><<<392, 256, 0, stream>>>(x, nullptr, wqh, bqkv,
                                           qsb, kbuf, vbuf, nullptr);

    // 2) neighborhood attention (v6c): 49 tiles x 4 heads x 8 batch, 256 thr
    natt_k<<<dim3(49, NH, 8), 256, 0, stream>>>(qsb, kbuf, vbuf, rpb, xh);

    // 3) output projection: 392 m-blocks, 2 internal n-phases, plain bf16
    gemm_fused<0><<<392, 256, 0, stream>>>(nullptr, xh, wph, bproj,
                                           nullptr, nullptr, nullptr, out);
}

// Round 20
// 52.194 us; speedup vs baseline: 1.1358x; 1.0317x over previous
//
#include <hip/hip_runtime.h>
#include <hip/hip_bf16.h>
#include <hip/hip_fp16.h>

#define NH 4
#define HD 32
#define PAD 3
#define HW 56
#define NPIX (8*HW*HW)          // 25088 pixels
#define SCALE 0.17677669529663687f

// ---------------- workspace layout (bytes) ----------------
// qs    : fp16 [8][4][56][56][32]    6,422,528  (q, pre-scaled)
// kbuf  : fp16 [8][4][56][56][32]    6,422,528
// vbuf  : fp16 [8][4][56][56][32]    6,422,528
// xh    : fp16 [25088][128]          6,422,528  (attn from natt)
// W fp16: wqh 98,304; wph 32,768
#define QS_OFF   0
#define K_OFF    12845056
#define V_OFF    (K_OFF + 6422528)
#define XH_OFF   (V_OFF + 6422528)      // attn (written by natt)
#define XL_OFF   (XH_OFF + 6422528)     // (unused)
#define WQH_OFF  (XL_OFF + 6422528)
#define WPH_OFF  (WQH_OFF + 98304)

typedef __attribute__((ext_vector_type(8))) short short8v;
typedef __attribute__((ext_vector_type(4))) float f32x4;

__device__ __forceinline__ unsigned short f2h(float x) {       // f32 -> fp16 bits, RNE
    return __half_as_ushort(__float2half_rn(x));
}

// packed-fp16 8-dot with f32 finish: 2 chains of {mul2, fma2} + hadd2 + 2 cvt
__device__ __forceinline__ float dot8h(const __half2* q2, uint4 k) {
    __half2 k0 = *(__half2*)&k.x, k1 = *(__half2*)&k.y;
    __half2 k2 = *(__half2*)&k.z, k3 = *(__half2*)&k.w;
    __half2 a = __hmul2(q2[0], k0);
    a = __hfma2(q2[1], k1, a);
    __half2 b = __hmul2(q2[2], k2);
    b = __hfma2(q2[3], k3, b);
    __half2 s2 = __hadd2(a, b);
    return __low2float(s2) + __high2float(s2);
}

// quad (4-lane) sum via DPP quad_perm: xor1 = 0xB1, xor2 = 0x4E. VALU-only.
__device__ __forceinline__ float quad_sum(float x) {
    x += __int_as_float(__builtin_amdgcn_update_dpp(0, __float_as_int(x), 0xB1, 0xF, 0xF, true));
    x += __int_as_float(__builtin_amdgcn_update_dpp(0, __float_as_int(x), 0x4E, 0xF, 0xF, true));
    return x;
}

// ---------------------------------------------------------------------------
// Weight convert (f32 -> fp16): W_qkv 12288 f4 + W_proj 4096 f4.
// ---------------------------------------------------------------------------
__global__ __launch_bounds__(256) void split_k(
    const float* __restrict__ wq, const float* __restrict__ wp,
    unsigned short* __restrict__ wqh, unsigned short* __restrict__ wph)
{
    int idx = blockIdx.x * 256 + threadIdx.x;
    if (idx >= 16384) return;
    const float* src; unsigned short* dh; int off;
    if (idx < 12288) { src = wq; dh = wqh; off = idx; }
    else             { src = wp; dh = wph; off = idx - 12288; }
    float4 v = ((const float4*)src)[off];
    ushort4 h;
    h.x = f2h(v.x); h.y = f2h(v.y); h.z = f2h(v.z); h.w = f2h(v.w);
    ((ushort4*)dh)[off] = h;
}

// ---------------------------------------------------------------------------
// Fused-N MFMA GEMM, plain fp16 (1 MFMA/frag, mfma_f32_16x16x32_f16 — same
// fragment layout as bf16, dtype-independent). fp16 storage is strictly
// FINER than bf16 (2^-11 vs 2^-9 mantissa) -> accuracy >= round 19's.
// grid = 392 m-blocks; A-tile staged once; NPH n-phases restage 16 KB B.
//  SELQKV=1: NPH=6, A = f32 x -> fp16 in-kernel; q/k/v scatter epilogue.
//  SELQKV=0: NPH=2, A = attn fp16; f32-row epilogue.
// LDS 32 KB.  XOR swizzle byte ^= (row&7)<<4 -> conflict-free b128 reads.
// ---------------------------------------------------------------------------
template <int SELQKV>
__global__ __launch_bounds__(256, 2) void gemm_fused(
    const float* __restrict__ Af32,
    const unsigned short* __restrict__ Axh,
    const unsigned short* __restrict__ Bgh,
    const float* __restrict__ bias,
    unsigned short* __restrict__ outq, unsigned short* __restrict__ outk,
    unsigned short* __restrict__ outv, float* __restrict__ outp)
{
    __shared__ unsigned short sAh[64 * 128];
    __shared__ unsigned short sBh[64 * 128];

    const int tid = threadIdx.x;
    const int m0 = blockIdx.x * 64;
    constexpr int NPH = SELQKV ? 6 : 2;

    // ---- stage A once (fp16) ----
    if constexpr (SELQKV) {
#pragma unroll
        for (int it = 0; it < 8; ++it) {
            int idx = tid + it * 256;          // 0..2047 float4 chunks
            int row = idx >> 5;                // 0..63
            int c4  = idx & 31;
            float4 a = *(const float4*)(Af32 + (size_t)(m0 + row) * 128 + c4 * 4);
            int byte = (row * 256 + c4 * 8) ^ ((row & 7) << 4);
            ushort4 h;
            h.x = f2h(a.x); h.y = f2h(a.y); h.z = f2h(a.z); h.w = f2h(a.w);
            *(ushort4*)((char*)sAh + byte) = h;
        }
    } else {
#pragma unroll
        for (int it = 0; it < 4; ++it) {
            int chunk = it * 256 + tid;        // 0..1023
            int row = chunk >> 4, c16 = chunk & 15;
            int byte = (row * 256 + c16 * 16) ^ ((row & 7) << 4);
            size_t ga = (size_t)(m0 + row) * 128 + c16 * 8;
            *(uint4*)((char*)sAh + byte) = *(const uint4*)(Axh + ga);
        }
    }

    const int lane = tid & 63;
    const int w  = tid >> 6;
    const int wr = w >> 1, wc = w & 1;       // 2x2 waves -> 64x64
    const int fr  = lane & 15;
    const int kqb = (lane >> 4) * 16;        // k byte offset within 64B group
    const int cl = lane & 15;
    const int rq = lane >> 4;

    for (int ph = 0; ph < NPH; ++ph) {
        const int n0 = ph * 64;
        if (ph > 0) __syncthreads();         // prior mfma reads done before B overwrite
#pragma unroll
        for (int it = 0; it < 4; ++it) {
            int chunk = it * 256 + tid;      // 0..1023
            int row = chunk >> 4, c16 = chunk & 15;
            int byte = (row * 256 + c16 * 16) ^ ((row & 7) << 4);
            size_t gb = (size_t)(n0 + row) * 128 + c16 * 8;
            *(uint4*)((char*)sBh + byte) = *(const uint4*)(Bgh + gb);
        }
        __syncthreads();

        f32x4 acc[2][2];
#pragma unroll
        for (int i = 0; i < 2; ++i)
#pragma unroll
            for (int j = 0; j < 2; ++j) acc[i][j] = (f32x4){0.f, 0.f, 0.f, 0.f};

#pragma unroll
        for (int ks = 0; ks < 4; ++ks) {
            short8v ah[2], bh[2];
#pragma unroll
            for (int mi = 0; mi < 2; ++mi) {
                int row = wr * 32 + mi * 16 + fr;
                int byte = (row * 256 + ks * 64 + kqb) ^ ((row & 7) << 4);
                ah[mi] = *(const short8v*)((const char*)sAh + byte);
            }
#pragma unroll
            for (int ni = 0; ni < 2; ++ni) {
                int row = wc * 32 + ni * 16 + fr;
                int byte = (row * 256 + ks * 64 + kqb) ^ ((row & 7) << 4);
                bh[ni] = *(const short8v*)((const char*)sBh + byte);
            }
#pragma unroll
            for (int mi = 0; mi < 2; ++mi)
#pragma unroll
                for (int ni = 0; ni < 2; ++ni)
                    acc[mi][ni] = __builtin_amdgcn_mfma_f32_16x16x32_f16(ah[mi], bh[ni], acc[mi][ni], 0, 0, 0);
        }

        // ---- epilogue: C/D layout col=lane&15, row=4*(lane>>4)+reg ----
#pragma unroll
        for (int mi = 0; mi < 2; ++mi) {
#pragma unroll
            for (int reg = 0; reg < 4; ++reg) {
                int m = m0 + wr * 32 + mi * 16 + rq * 4 + reg;
                if constexpr (SELQKV) {
                    int b = m / 3136;
                    int r = m - b * 3136;
                    int y = r / 56;
                    int x = r - y * 56;
#pragma unroll
                    for (int ni = 0; ni < 2; ++ni) {
                        int nn = n0 + wc * 32 + ni * 16 + cl;   // 0..383
                        float val = acc[mi][ni][reg] + bias[nn];
                        int sel = nn >> 7;                      // 0=q 1=k 2=v
                        int nl = nn & 127;
                        int h = nl >> 5, d = nl & 31;
                        size_t oi = ((size_t)((b * NH + h) * 3136) + y * 56 + x) * 32 + d;
                        if (sel == 0)      outq[oi] = f2h(val * SCALE);   // q fp16
                        else if (sel == 1) outk[oi] = f2h(val);
                        else               outv[oi] = f2h(val);
                    }
                } else {
#pragma unroll
                    for (int ni = 0; ni < 2; ++ni) {
                        int nn = n0 + wc * 32 + ni * 16 + cl;
                        outp[(size_t)m * 128 + nn] = acc[mi][ni][reg] + bias[nn];
                    }
                }
            }
        }
    }
}

// ---------------------------------------------------------------------------
// Neighborhood attention v8 (fp16 packed QK path):
// 4 threads per (pixel,head) d-chunk split, 256 thr, 8x8 tile, halo 14x14,
// grid 49x4x8.  QK dot = 4 packed v_pk_fma_f16-class ops + f32 finish
// (was 8 fma + 8 bf16 unpacks); q kept packed in 4 half2 regs (no unpack).
// V unpacked to f32 in LDS at staging (PV axpy = plain fmaf, unchanged);
// attn output fp16 (1-op convert).  LDS 36.8 KB -> 4 blocks/CU.
// ---------------------------------------------------------------------------
__global__ __launch_bounds__(256, 4) void natt_k(
    const unsigned short* __restrict__ qs, const unsigned short* __restrict__ kb,
    const unsigned short* __restrict__ vb, const float* __restrict__ rpb,
    unsigned short* __restrict__ attn_h)
{
    __shared__ uint4 ks[196 * 4];                    // K fp16 [pix][c], 12544 B
    __shared__ __align__(16) float vfs[4][1572];     // V f32 c-sections, 25152 B

    const int tid = threadIdx.x;
    const int b = blockIdx.z, h = blockIdx.y;
    const int tyy = blockIdx.x / 7, txx = blockIdx.x - tyy * 7;  // 7x7 tiles
    const int y0 = tyy * 8, x0 = txx * 8;
    const int bh = b * NH + h;

    const int p = tid >> 2, c = tid & 3;   // quads 4-aligned -> DPP partners co-active
    const int py = p >> 3;
    const int pxx = p & 7;

    // hoisted q load (fp16, 16B) — stays packed in 4 half2 regs
    __half2 q2[4];
    {
        uint4 qv = *(const uint4*)(qs +
            ((size_t)(bh * 3136) + (y0 + py) * 56 + (x0 + pxx)) * 32 + c * 8);
        q2[0] = *(__half2*)&qv.x; q2[1] = *(__half2*)&qv.y;
        q2[2] = *(__half2*)&qv.z; q2[3] = *(__half2*)&qv.w;
    }

    const uint4* kg = (const uint4*)kb;  // 4 uint4 per pixel (32 fp16)
    const uint4* vg = (const uint4*)vb;
    for (int idx = tid; idx < 784; idx += 256) {   // 196 pix * 4 chunks
        int pix = idx >> 2, cc = idx & 3;
        int i = pix / 14;
        int j = pix - i * 14;
        int y = y0 + i - PAD;
        int x = x0 + j - PAD;
        uint4 zk = make_uint4(0u, 0u, 0u, 0u);
        uint4 zv = make_uint4(0u, 0u, 0u, 0u);
        if ((unsigned)y < 56u && (unsigned)x < 56u) {
            int g = ((bh * 3136) + y * 56 + x) * 4 + cc;
            zk = kg[g];
            zv = vg[g];
        }
        ks[idx] = zk;
        float2 f0 = __half22float2(*(__half2*)&zv.x);
        float2 f1 = __half22float2(*(__half2*)&zv.y);
        float2 f2 = __half22float2(*(__half2*)&zv.z);
        float2 f3 = __half22float2(*(__half2*)&zv.w);
        float* vd = &vfs[cc][pix * 8];
        vd[0] = f0.x; vd[1] = f0.y; vd[2] = f1.x; vd[3] = f1.y;
        vd[4] = f2.x; vd[5] = f2.y; vd[6] = f3.x; vd[7] = f3.y;
    }
    __syncthreads();

    float acc[8];
#pragma unroll
    for (int d = 0; d < 8; ++d) acc[d] = 0.f;
    float l = 0.f;

    const float* rph = rpb + h * 49;       // uniform index -> scalar loads
    const float* vbase = &vfs[c][0];

#pragma unroll
    for (int dy = 0; dy < 7; ++dy) {
        int rowpix = (py + dy) * 14 + pxx;
#pragma unroll
        for (int dx = 0; dx < 7; ++dx) {
            int pix = rowpix + dx;
            float s  = dot8h(q2, ks[pix * 4 + c]);
            float sf = quad_sum(s) + rph[dy * 7 + dx];
            float e  = __expf(sf);
            l += e;
            const float* vv = vbase + pix * 8;
            float4 v0 = *(const float4*)(vv);
            float4 v1 = *(const float4*)(vv + 4);
            acc[0] = fmaf(e, v0.x, acc[0]); acc[1] = fmaf(e, v0.y, acc[1]);
            acc[2] = fmaf(e, v0.z, acc[2]); acc[3] = fmaf(e, v0.w, acc[3]);
            acc[4] = fmaf(e, v1.x, acc[4]); acc[5] = fmaf(e, v1.y, acc[5]);
            acc[6] = fmaf(e, v1.z, acc[6]); acc[7] = fmaf(e, v1.w, acc[7]);
        }
    }

    float rl = 1.0f / l;

    // pack 8 dims -> fp16 uint4, single b128 store
    unsigned short hv[8];
#pragma unroll
    for (int d = 0; d < 8; ++d) hv[d] = f2h(acc[d] * rl);
    uint4 uh;
    uh.x = (unsigned)hv[0] | ((unsigned)hv[1] << 16);
    uh.y = (unsigned)hv[2] | ((unsigned)hv[3] << 16);
    uh.z = (unsigned)hv[4] | ((unsigned)hv[5] << 16);
    uh.w = (unsigned)hv[6] | ((unsigned)hv[7] << 16);

    size_t base = ((size_t)(b * 3136) + (y0 + py) * 56 + (x0 + pxx)) * 128 + h * 32 + c * 8;
    *(uint4*)(attn_h + base) = uh;
}

extern "C" void kernel_launch(void* const* d_in, const int* in_sizes, int n_in,
                              void* d_out, int out_size, void* d_ws, size_t ws_size,
                              hipStream_t stream)
{
    const float* x     = (const float*)d_in[0];
    const float* Wqkv  = (const float*)d_in[1];
    const float* bqkv  = (const float*)d_in[2];
    const float* rpb   = (const float*)d_in[3];
    const float* Wproj = (const float*)d_in[4];
    const float* bproj = (const float*)d_in[5];
    float* out = (float*)d_out;

    char* ws = (char*)d_ws;
    unsigned short* qsb  = (unsigned short*)(ws + QS_OFF);   // q fp16 (pre-scaled)
    unsigned short* kbuf = (unsigned short*)(ws + K_OFF);
    unsigned short* vbuf = (unsigned short*)(ws + V_OFF);
    unsigned short* xh   = (unsigned short*)(ws + XH_OFF);   // attn fp16 (from natt)
    unsigned short* wqh  = (unsigned short*)(ws + WQH_OFF);
    unsigned short* wph  = (unsigned short*)(ws + WPH_OFF);

    // 0) convert weights to fp16 (tiny)
    split_k<<<64, 256, 0, stream>>>(Wqkv, Wproj, wqh, wph);

    // 1) QKV projection: 392 m-blocks, 6 internal n-phases (A staged once,
    //    plain fp16 -> 1 MFMA/frag, 32 KB LDS)
    gemm_fused<1><<<392, 256, 0, stream>>>(x, nullptr, wqh, bqkv,
                                           qsb, kbuf, vbuf, nullptr);

    // 2) neighborhood attention (v8, packed fp16 QK): 49 x 4 x 8, 256 thr
    natt_k<<<dim3(49, NH, 8), 256, 0, stream>>>(qsb, kbuf, vbuf, rpb, xh);

    // 3) output projection: 392 m-blocks, 2 internal n-phases, plain fp16
    gemm_fused<0><<<392, 256, 0, stream>>>(nullptr, xh, wph, bproj,
                                           nullptr, nullptr, nullptr, out);
}